// Round 14
// baseline (697.145 us; speedup 1.0000x reference)
//
#include <hip/hip_runtime.h>
#include <hip/hip_bf16.h>
#include <math.h>

typedef __hip_bfloat16 bf16;
typedef __attribute__((ext_vector_type(8))) short short8;
typedef __attribute__((ext_vector_type(4))) float float4v;
typedef __attribute__((ext_vector_type(2))) float float2v;
typedef __attribute__((ext_vector_type(2))) unsigned short ushort2v;
typedef __attribute__((ext_vector_type(4))) unsigned short ushort4v;

#define N_NODES_C 100000
#define N_EDGES_C 600000
#define N_CENTER_C 512
#define N_NONMOL_C 20000
#define N_REL_C 50
#define D_C 128
#define N_MOTIF_C 85

// element offsets into d_out (dtype-independent)
#define EO_EDGE  0L
#define EO_MOTIF 30000000L
#define EO_NODEC 30043520L
#define EO_BIN   30343520L

// byte offsets of scratch inside d_out (dead before any output is written;
// edge_out (first writer of d_out[0..60MB)) runs after all scratch consumers)
#define AGG_OFF  0L
#define ET_OFF   51200000L
#define WT0_OFF  51225600L
#define WT1_OFF  51258368L
#define WT2_OFF  51291136L
#define BPQ_OFF  51323904L
#define LB_OFF   51352576L
#define B1_OFF   51353088L
#define B2_OFF   51353600L
#define OFFS_OFF 51354112L
#define BSUM_OFF 51755680L
#define SSRC_OFF 51757248L
#define SREL_OFF 54157248L
#define SDST_OFF 56557248L
// ends 58,957,248 < 60,887,040 (min d_out size, bf16 case)

#define EPW_C 32   // edges per wave in gather_agg2 (divides N_EDGES_C exactly)

__device__ __forceinline__ float b2f(bf16 v) { return __bfloat162float(v); }
__device__ __forceinline__ float bits2f(unsigned short s) {
    unsigned u = ((unsigned)s) << 16; float f; __builtin_memcpy(&f, &u, 4); return f;
}
__device__ __forceinline__ unsigned short f2bits(float f) {
    bf16 h = __float2bfloat16(f); unsigned short s; __builtin_memcpy(&s, &h, 2); return s;
}
__device__ __forceinline__ float ldf(const void* p, size_t i, int isbf) {
    return isbf ? __bfloat162float(((const bf16*)p)[i]) : ((const float*)p)[i];
}
// non-temporal final-output store (neutral on perf per round-12 A/B; harmless)
__device__ __forceinline__ void stout_nt(void* p, size_t i, int isbf, float v) {
    if (isbf) __builtin_nontemporal_store(f2bits(v), (unsigned short*)p + i);
    else      __builtin_nontemporal_store(v, (float*)p + i);
}

// ---- dtype probe ----
__global__ void probe_kernel(const void* __restrict__ table, int* __restrict__ flag) {
    __shared__ int bad[256];
    int t = threadIdx.x;
    const bf16* p = (const bf16*)table;
    int cnt = 0;
    for (int i = 0; i < 64; i++) {
        float v = __bfloat162float(p[t * 64 + i]);
        if (!isfinite(v) || fabsf(v) > 1000.0f) cnt++;
    }
    bad[t] = cnt;
    __syncthreads();
    for (int s = 128; s > 0; s >>= 1) {
        if (t < s) bad[t] += bad[t + s];
        __syncthreads();
    }
    if (t == 0) *flag = (bad[0] == 0) ? 1 : 0;   // 1 = bf16, 0 = fp32
}

// ---- prepack: WT[n][k] = W[k][n] (bf16), BPQ[j][k] from edge_W, biases fp32 ----
__global__ void prepack_kernel(const int* __restrict__ flag,
                               const void* __restrict__ linW, const void* __restrict__ w1,
                               const void* __restrict__ w2, const void* __restrict__ edgeW,
                               const void* __restrict__ linb, const void* __restrict__ bb1,
                               const void* __restrict__ bb2,
                               unsigned short* __restrict__ WT0, unsigned short* __restrict__ WT1,
                               unsigned short* __restrict__ WT2, unsigned short* __restrict__ BPQ,
                               float* __restrict__ LB, float* __restrict__ B1p, float* __restrict__ B2p) {
    int isbf = *flag;
    int g = blockIdx.x * 256 + threadIdx.x;
    if (g < 3 * 16384) {
        int w = g / 16384, i = g % 16384;
        int n = i >> 7, k = i & 127;
        const void* src = (w == 0) ? linW : (w == 1) ? w1 : w2;
        unsigned short* dst = (w == 0) ? WT0 : (w == 1) ? WT1 : WT2;
        dst[i] = f2bits(ldf(src, (size_t)k * 128 + n, isbf));
    } else if (g < 3 * 16384 + 112 * 128) {
        int i = g - 3 * 16384;
        int j = i >> 7, k = i & 127;
        float v = 0.0f;
        if (j < 50)       v = ldf(edgeW, (size_t)k * 50 + j, isbf);
        else if (j < 100) v = ldf(edgeW, (size_t)(128 + k) * 50 + (j - 50), isbf);
        BPQ[i] = f2bits(v);
    } else if (g < 3 * 16384 + 112 * 128 + 3 * 128) {
        int i = g - (3 * 16384 + 112 * 128);
        int w = i >> 7, n = i & 127;
        const void* src = (w == 0) ? linb : (w == 1) ? bb1 : bb2;
        float* dst = (w == 0) ? LB : (w == 1) ? B1p : B2p;
        dst[n] = ldf(src, n, isbf);
    }
}

// ---- ET (50 rows only): relu(l2norm(rel_emb) @ lin_W + lin_b) fp32 ----
__global__ void et_kernel(const int* __restrict__ flag,
                          const void* __restrict__ table,
                          const void* __restrict__ W,
                          const void* __restrict__ bias,
                          float* __restrict__ out) {
    int isbf = *flag;
    int row = blockIdx.x;
    int t = threadIdx.x;
    float v = ldf(table, (size_t)row * D_C + t, isbf);
    __shared__ float sv[D_C];
    __shared__ float red[D_C];
    red[t] = v * v;
    __syncthreads();
    for (int s = 64; s > 0; s >>= 1) {
        if (t < s) red[t] += red[t + s];
        __syncthreads();
    }
    float nrm = fmaxf(sqrtf(red[0]), 1e-12f);
    sv[t] = v / nrm;
    __syncthreads();
    float acc = ldf(bias, t, isbf);
    for (int k = 0; k < D_C; k++) acc = fmaf(sv[k], ldf(W, k * D_C + t, isbf), acc);
    out[(size_t)row * D_C + t] = fmaxf(acc, 0.0f);
}

// ---- normalize: one wave per row, 2 elems/lane ----
__global__ void normalize_kernel(const int* __restrict__ flag,
                                 const int* __restrict__ ids,
                                 const void* __restrict__ table,
                                 unsigned short* __restrict__ out) {
    int w = (int)((blockIdx.x * (long)blockDim.x + threadIdx.x) >> 6);
    int lane = threadIdx.x & 63;
    if (w >= N_NODES_C) return;
    int isbf = *flag;
    int id = ids[w];
    float v0, v1;
    if (isbf) {
        const unsigned short* p = (const unsigned short*)table + (size_t)id * D_C + lane * 2;
        ushort2 u = *(const ushort2*)p;
        v0 = bits2f(u.x); v1 = bits2f(u.y);
    } else {
        const float* p = (const float*)table + (size_t)id * D_C + lane * 2;
        float2 f = *(const float2*)p;
        v0 = f.x; v1 = f.y;
    }
    float ss = v0 * v0 + v1 * v1;
#pragma unroll
    for (int o = 32; o > 0; o >>= 1) ss += __shfl_down(ss, o, 64);
    ss = __shfl(ss, 0, 64);
    float inv = 1.0f / fmaxf(sqrtf(ss), 1e-12f);
    ushort2 o2;
    o2.x = f2bits(v0 * inv);
    o2.y = f2bits(v1 * inv);
    *(ushort2*)(out + (size_t)w * D_C + lane * 2) = o2;
}

// ---- MFMA GEMM: Y[M,NOUT] = act((X[+AGG]) @ BT^T + bias), K=128 resident ----
template <int NOUT, bool RELU, bool ADD_AGG, bool HAS_BIAS>
__global__ __launch_bounds__(256, 2) void gemm_kernel(
        const unsigned short* __restrict__ X,   // [M,128] bf16 bits
        const float* __restrict__ AGG,          // [M,128] fp32 (or null)
        const unsigned short* __restrict__ BT,  // [NT*16,128] bf16 bits, row n holds W[:,n]
        const float* __restrict__ bias,         // [NOUT] fp32 (or null)
        unsigned short* __restrict__ Y,         // [M,NOUT] bf16 bits
        int M) {
    constexpr int NT = (NOUT + 15) / 16;
    __shared__ short Als[128 * 128];
    __shared__ short Bls[NT * 16 * 128];
    int t = threadIdx.x;
    int m0 = blockIdx.x * 128;

#pragma unroll
    for (int p = 0; p < 8; p++) {
        int lin = (p * 256 + t) * 8;
        int row = lin >> 7, col = lin & 127;
        int gr = m0 + row; if (gr >= M) gr = M - 1;
        short8 xv = *(const short8*)(X + (size_t)gr * 128 + col);
        if (ADD_AGG) {
            const float* ap = AGG + (size_t)gr * 128 + col;
            float4v a0 = *(const float4v*)ap;
            float4v a1 = *(const float4v*)(ap + 4);
            short8 r;
#pragma unroll
            for (int i = 0; i < 4; i++) r[i] = (short)f2bits(bits2f((unsigned short)xv[i]) + a0[i]);
#pragma unroll
            for (int i = 0; i < 4; i++) r[4 + i] = (short)f2bits(bits2f((unsigned short)xv[4 + i]) + a1[i]);
            xv = r;
        }
        *(short8*)&Als[lin] = xv;
    }
    constexpr int BELEMS = NT * 16 * 128;
#pragma unroll
    for (int p = 0; p * 2048 < BELEMS; p++) {
        int lin = (p * 256 + t) * 8;
        if (lin < BELEMS) *(short8*)&Bls[lin] = *(const short8*)(BT + lin);
    }
    __syncthreads();

    int wave = t >> 6, lane = t & 63;
    int quad = lane >> 4, lr = lane & 15;
    int wr0 = wave * 32;

    short8 afr[2][4];
#pragma unroll
    for (int mt = 0; mt < 2; mt++)
#pragma unroll
        for (int kk = 0; kk < 4; kk++)
            afr[mt][kk] = *(short8*)&Als[(wr0 + mt * 16 + lr) * 128 + kk * 32 + quad * 8];

#pragma unroll
    for (int nt = 0; nt < NT; nt++) {
        short8 bfr[4];
#pragma unroll
        for (int kk = 0; kk < 4; kk++)
            bfr[kk] = *(short8*)&Bls[(nt * 16 + lr) * 128 + kk * 32 + quad * 8];
        int col = nt * 16 + lr;
        float bs = 0.0f;
        if (HAS_BIAS) bs = bias[col];
#pragma unroll
        for (int mt = 0; mt < 2; mt++) {
            float4v acc = {0.0f, 0.0f, 0.0f, 0.0f};
#pragma unroll
            for (int kk = 0; kk < 4; kk++)
                acc = __builtin_amdgcn_mfma_f32_16x16x32_bf16(afr[mt][kk], bfr[kk], acc, 0, 0, 0);
            int rbase = m0 + wr0 + mt * 16 + quad * 4;
#pragma unroll
            for (int r = 0; r < 4; r++) {
                int row = rbase + r;
                float v = acc[r] + bs;
                if (RELU) v = fmaxf(v, 0.0f);
                if (row < M && ((NOUT & 15) == 0 || col < NOUT))
                    Y[(size_t)row * NOUT + col] = f2bits(v);
            }
        }
    }
}

// ================= counting sort of edges by dst =================
__global__ void hist_kernel(const int* __restrict__ ei, int* __restrict__ cnt) {
    int e = blockIdx.x * 256 + threadIdx.x;
    if (e < N_EDGES_C) atomicAdd(&cnt[ei[N_EDGES_C + e]], 1);
}

// in-place: cnt -> exclusive-scan-within-block; bsum[b] = block total
__global__ void scan1_kernel(int* __restrict__ cnt, int* __restrict__ bsum) {
    __shared__ int s[256];
    int t = threadIdx.x;
    int idx = blockIdx.x * 256 + t;
    int v = (idx < N_NODES_C) ? cnt[idx] : 0;
    s[t] = v;
    __syncthreads();
    for (int o = 1; o < 256; o <<= 1) {
        int u = (t >= o) ? s[t - o] : 0;
        __syncthreads();
        s[t] += u;
        __syncthreads();
    }
    if (idx < N_NODES_C) cnt[idx] = s[t] - v;     // exclusive within block
    if (t == 255) bsum[blockIdx.x] = s[255];      // block total
}

// single block: bsum -> exclusive scan (NB=391 <= 512)
__global__ void scan2_kernel(int* __restrict__ bsum, int nb) {
    __shared__ int s[512];
    int t = threadIdx.x;
    int v = (t < nb) ? bsum[t] : 0;
    s[t] = v;
    __syncthreads();
    for (int o = 1; o < 512; o <<= 1) {
        int u = (t >= o) ? s[t - o] : 0;
        __syncthreads();
        s[t] += u;
        __syncthreads();
    }
    if (t < nb) bsum[t] = s[t] - v;               // exclusive
}

__global__ void scan3_kernel(int* __restrict__ cnt, const int* __restrict__ bsum) {
    int idx = blockIdx.x * 256 + threadIdx.x;
    if (idx < N_NODES_C) cnt[idx] += bsum[blockIdx.x];
}

// place edges; after this, offs[n] = end of segment n (start = offs[n-1], offs[-1]=0)
__global__ void sort_scatter_kernel(const int* __restrict__ ei, const int* __restrict__ rel,
                                    int* __restrict__ offs,
                                    int* __restrict__ ssrc, int* __restrict__ srel,
                                    int* __restrict__ sdst) {
    int e = blockIdx.x * 256 + threadIdx.x;
    if (e >= N_EDGES_C) return;
    int dst = ei[N_EDGES_C + e];
    int pos = atomicAdd(&offs[dst], 1);
    ssrc[pos] = ei[e];
    srel[pos] = rel[e];
    sdst[pos] = dst;
}

// ---- edge-parallel segmented sum over dst-sorted edges ----
// One wave per EPW_C-edge chunk; lane l accumulates feats 2l, 2l+1.
// 8-edge unrolled batches: MLP=8 on the random x-row loads (latency-bound).
// Interior segments -> plain store; chunk-boundary -> atomicAdd (AGG pre-zeroed).
__global__ __launch_bounds__(256) void gather_agg2_kernel(
        const unsigned short* __restrict__ x,
        const int* __restrict__ ssrc, const int* __restrict__ srel,
        const int* __restrict__ sdst,
        const float* __restrict__ etab,
        float* __restrict__ agg) {
    int w = (int)((blockIdx.x * 256u + threadIdx.x) >> 6);
    int lane = threadIdx.x & 63;
    int e0 = w * EPW_C;
    if (e0 >= N_EDGES_C) return;

    float a0 = 0.0f, a1 = 0.0f;
    int cur = sdst[e0];
    bool first = true;                 // current segment may have started before e0

    for (int e = e0; e < e0 + EPW_C; e += 8) {
        int4 sva = *(const int4*)(ssrc + e);
        int4 svb = *(const int4*)(ssrc + e + 4);
        int4 rva = *(const int4*)(srel + e);
        int4 rvb = *(const int4*)(srel + e + 4);
        int4 dva = *(const int4*)(sdst + e);
        int4 dvb = *(const int4*)(sdst + e + 4);
        int s_[8] = {sva.x, sva.y, sva.z, sva.w, svb.x, svb.y, svb.z, svb.w};
        int r_[8] = {rva.x, rva.y, rva.z, rva.w, rvb.x, rvb.y, rvb.z, rvb.w};
        int d_[8] = {dva.x, dva.y, dva.z, dva.w, dvb.x, dvb.y, dvb.z, dvb.w};
        ushort2 uu[8];
        float2 tt[8];
        // issue all 8 x-row + 8 etab loads before consuming: MLP=8
#pragma unroll
        for (int j = 0; j < 8; j++) uu[j] = *(const ushort2*)(x + (size_t)s_[j] * D_C + lane * 2);
#pragma unroll
        for (int j = 0; j < 8; j++) tt[j] = *(const float2*)(etab + r_[j] * D_C + lane * 2);
#pragma unroll
        for (int j = 0; j < 8; j++) {
            if (d_[j] != cur) {
                float* p = agg + (size_t)cur * D_C + lane * 2;
                if (first) { atomicAdd(p, a0); atomicAdd(p + 1, a1); }
                else       { p[0] = a0; p[1] = a1; }
                first = false; a0 = 0.0f; a1 = 0.0f; cur = d_[j];
            }
            a0 += fmaxf(bits2f(uu[j].x) + tt[j].x, 0.0f);
            a1 += fmaxf(bits2f(uu[j].y) + tt[j].y, 0.0f);
        }
    }
    // final flush: plain store only if segment both started and ended inside chunk
    bool endshere = (e0 + EPW_C >= N_EDGES_C) || (sdst[e0 + EPW_C] != cur);
    float* p = agg + (size_t)cur * D_C + lane * 2;
    if (!first && endshere) { p[0] = a0; p[1] = a1; }
    else { atomicAdd(p, a0); atomicAdd(p + 1, a1); }
}

// ---- edge head, 4-wide quads: 13 units/edge (12 quads + 1 pair) ----
// src half: 8B ushort4 (byte off 200*src+2j, j%4==0 -> 8B-aligned);
// dst half: two 4B ushort2 (the +100 byte offset breaks 8B alignment);
// stores: two float2 (fp32) / two ushort2 (bf16) — alignment-safe for odd e.
__global__ void edge_out_kernel(const int* __restrict__ flag,
                                const int* __restrict__ ei,
                                const unsigned short* __restrict__ PQ,
                                const void* __restrict__ eb,
                                void* __restrict__ out) {
    int isbf = *flag;
    long g = (long)blockIdx.x * blockDim.x + threadIdx.x;
    if (g >= (long)N_EDGES_C * 13) return;
    int e = (int)(g / 13);
    int jq = (int)(g - (long)e * 13);
    int src = ei[e];
    int dst = ei[N_EDGES_C + e];
    if (jq < 12) {
        int j = jq * 4;
        ushort4v us = *(const ushort4v*)(PQ + (size_t)src * 100 + j);
        ushort2v ud0 = *(const ushort2v*)(PQ + (size_t)dst * 100 + 50 + j);
        ushort2v ud1 = *(const ushort2v*)(PQ + (size_t)dst * 100 + 50 + j + 2);
        float v0 = bits2f(us.x) + bits2f(ud0.x) + ldf(eb, j, isbf);
        float v1 = bits2f(us.y) + bits2f(ud0.y) + ldf(eb, j + 1, isbf);
        float v2 = bits2f(us.z) + bits2f(ud1.x) + ldf(eb, j + 2, isbf);
        float v3 = bits2f(us.w) + bits2f(ud1.y) + ldf(eb, j + 3, isbf);
        if (isbf) {
            ushort2v o0; o0.x = f2bits(v0); o0.y = f2bits(v1);
            ushort2v o1; o1.x = f2bits(v2); o1.y = f2bits(v3);
            unsigned short* ob = (unsigned short*)out + EO_EDGE + (size_t)e * 50 + j;
            __builtin_nontemporal_store(o0, (ushort2v*)ob);
            __builtin_nontemporal_store(o1, (ushort2v*)(ob + 2));
        } else {
            float2v o0; o0.x = v0; o0.y = v1;
            float2v o1; o1.x = v2; o1.y = v3;
            float* ob = (float*)out + EO_EDGE + (size_t)e * 50 + j;
            __builtin_nontemporal_store(o0, (float2v*)ob);
            __builtin_nontemporal_store(o1, (float2v*)(ob + 2));
        }
    } else {
        int j = 48;
        ushort2v us = *(const ushort2v*)(PQ + (size_t)src * 100 + j);
        ushort2v ud = *(const ushort2v*)(PQ + (size_t)dst * 100 + 50 + j);
        float v0 = bits2f(us.x) + bits2f(ud.x) + ldf(eb, j, isbf);
        float v1 = bits2f(us.y) + bits2f(ud.y) + ldf(eb, j + 1, isbf);
        if (isbf) {
            ushort2v o; o.x = f2bits(v0); o.y = f2bits(v1);
            __builtin_nontemporal_store(o, (ushort2v*)((unsigned short*)out + EO_EDGE + (size_t)e * 50 + j));
        } else {
            float2v o; o.x = v0; o.y = v1;
            __builtin_nontemporal_store(o, (float2v*)((float*)out + EO_EDGE + (size_t)e * 50 + j));
        }
    }
}

__global__ void motif_kernel(const int* __restrict__ flag,
                             const int* __restrict__ cidx,
                             const bf16* __restrict__ x,
                             const void* __restrict__ W,
                             const void* __restrict__ bias,
                             void* __restrict__ out) {
    int isbf = *flag;
    int row = blockIdx.x;
    int t = threadIdx.x;
    __shared__ float sv[D_C];
    int id = cidx[row];
    sv[t] = b2f(x[(size_t)id * D_C + t]);
    __syncthreads();
    if (t < N_MOTIF_C) {
        float acc = ldf(bias, t, isbf);
        for (int k = 0; k < D_C; k++) acc = fmaf(sv[k], ldf(W, k * N_MOTIF_C + t, isbf), acc);
        stout_nt(out, EO_MOTIF + (size_t)row * N_MOTIF_C + t, isbf, acc);
    }
}

__global__ void nodec_kernel(const int* __restrict__ flag,
                             const int* __restrict__ nidx,
                             const bf16* __restrict__ x,
                             const void* __restrict__ W,
                             const void* __restrict__ bias,
                             void* __restrict__ out) {
    int isbf = *flag;
    int g = blockIdx.x * blockDim.x + threadIdx.x;
    if (g >= N_NONMOL_C * 15) return;
    int row = g / 15;
    int j = g - row * 15;
    int id = nidx[row];
    float acc = ldf(bias, j, isbf);
    for (int k = 0; k < D_C; k++) acc = fmaf(b2f(x[(size_t)id * D_C + k]), ldf(W, k * 15 + j, isbf), acc);
    stout_nt(out, EO_NODEC + g, isbf, acc);
}

__global__ void binary_kernel(const int* __restrict__ flag,
                              const bf16* __restrict__ x,
                              const void* __restrict__ W,
                              const void* __restrict__ bias,
                              void* __restrict__ out) {
    int isbf = *flag;
    int g = blockIdx.x * blockDim.x + threadIdx.x;
    int row = g >> 6;
    int lane = threadIdx.x & 63;
    if (row >= N_NODES_C) return;
    float a = b2f(x[(size_t)row * D_C + lane]) * ldf(W, lane, isbf) +
              b2f(x[(size_t)row * D_C + 64 + lane]) * ldf(W, 64 + lane, isbf);
#pragma unroll
    for (int off = 32; off > 0; off >>= 1) a += __shfl_down(a, off, 64);
    if (lane == 0) stout_nt(out, EO_BIN + row, isbf, a + ldf(bias, 0, isbf));
}

extern "C" void kernel_launch(void* const* d_in, const int* in_sizes, int n_in,
                              void* d_out, int out_size, void* d_ws, size_t ws_size,
                              hipStream_t stream) {
    const int* node_ids = (const int*)d_in[0];
    const int* rel_ids  = (const int*)d_in[1];
    const int* center   = (const int*)d_in[2];
    const int* nonmol   = (const int*)d_in[3];
    const int* ei       = (const int*)d_in[4];
    const void* node_emb = d_in[5];
    const void* rel_emb  = d_in[6];
    const void* lin_W = d_in[7];
    const void* lin_b = d_in[8];
    const void* W1 = d_in[9];
    const void* b1 = d_in[10];
    const void* W2 = d_in[11];
    const void* b2 = d_in[12];
    const void* edge_W = d_in[13];
    const void* edge_b = d_in[14];
    const void* motif_W = d_in[15];
    const void* motif_b = d_in[16];
    const void* nodec_W = d_in[17];
    const void* nodec_b = d_in[18];
    const void* bin_W = d_in[19];
    const void* bin_b = d_in[20];

    // ws: X0 [0,25.6MB), X1 [25.6,51.2MB), FLAG (4B)
    char* wsb = (char*)d_ws;
    unsigned short* X0 = (unsigned short*)wsb;
    unsigned short* X1 = (unsigned short*)(wsb + (size_t)N_NODES_C * D_C * 2);
    int* FLAG = (int*)(wsb + (size_t)2 * N_NODES_C * D_C * 2);
    unsigned short* PQ = X1;

    // scratch carved from dead d_out space
    char* ob = (char*)d_out;
    float* AGG = (float*)(ob + AGG_OFF);
    float* ET  = (float*)(ob + ET_OFF);
    unsigned short* WT0 = (unsigned short*)(ob + WT0_OFF);
    unsigned short* WT1 = (unsigned short*)(ob + WT1_OFF);
    unsigned short* WT2 = (unsigned short*)(ob + WT2_OFF);
    unsigned short* BPQ = (unsigned short*)(ob + BPQ_OFF);
    float* LB  = (float*)(ob + LB_OFF);
    float* B1p = (float*)(ob + B1_OFF);
    float* B2p = (float*)(ob + B2_OFF);
    int* OFFS = (int*)(ob + OFFS_OFF);
    int* BSUM = (int*)(ob + BSUM_OFF);
    int* SSRC = (int*)(ob + SSRC_OFF);
    int* SREL = (int*)(ob + SREL_OFF);
    int* SDST = (int*)(ob + SDST_OFF);

    const int gemm_blocks = (N_NODES_C + 127) / 128;   // 782
    const int nscan = (N_NODES_C + 255) / 256;         // 391
    const int eblocks = (N_EDGES_C + 255) / 256;
    const int g2_waves = N_EDGES_C / EPW_C;            // 18750 (exact)
    const int g2_blocks = (g2_waves + 3) / 4;          // 4 waves/block

    probe_kernel<<<1, 256, 0, stream>>>(node_emb, FLAG);
    prepack_kernel<<<250, 256, 0, stream>>>(FLAG, lin_W, W1, W2, edge_W, lin_b, b1, b2,
                                            WT0, WT1, WT2, BPQ, LB, B1p, B2p);
    et_kernel<<<N_REL_C, D_C, 0, stream>>>(FLAG, rel_emb, lin_W, lin_b, ET);

    // ---- counting sort of edges by dst (reused by both convs) ----
    hipMemsetAsync(OFFS, 0, N_NODES_C * sizeof(int), stream);
    hist_kernel<<<eblocks, 256, 0, stream>>>(ei, OFFS);
    scan1_kernel<<<nscan, 256, 0, stream>>>(OFFS, BSUM);
    scan2_kernel<<<1, 512, 0, stream>>>(BSUM, nscan);
    scan3_kernel<<<nscan, 256, 0, stream>>>(OFFS, BSUM);
    sort_scatter_kernel<<<eblocks, 256, 0, stream>>>(ei, rel_ids, OFFS, SSRC, SREL, SDST);

    // X0 = l2norm(node_emb[node_ids]), then in-place X0 = relu(X0 @ lin_W + lin_b)
    normalize_kernel<<<(N_NODES_C * 64 + 255) / 256, 256, 0, stream>>>(FLAG, node_ids, node_emb, X0);
    gemm_kernel<128, true, false, true><<<gemm_blocks, 256, 0, stream>>>(X0, nullptr, WT0, LB, X0, N_NODES_C);

    // GINE conv 1: X1 = relu((X0 + AGG) @ W1 + b1)
    hipMemsetAsync(AGG, 0, (size_t)N_NODES_C * D_C * sizeof(float), stream);
    gather_agg2_kernel<<<g2_blocks, 256, 0, stream>>>(X0, SSRC, SREL, SDST, ET, AGG);
    gemm_kernel<128, true, true, true><<<gemm_blocks, 256, 0, stream>>>(X0, AGG, WT1, B1p, X1, N_NODES_C);

    // GINE conv 2: X2(=X0 slot) = (X1 + AGG) @ W2 + b2
    hipMemsetAsync(AGG, 0, (size_t)N_NODES_C * D_C * sizeof(float), stream);
    gather_agg2_kernel<<<g2_blocks, 256, 0, stream>>>(X1, SSRC, SREL, SDST, ET, AGG);
    gemm_kernel<128, false, true, true><<<gemm_blocks, 256, 0, stream>>>(X1, AGG, WT2, B2p, X0, N_NODES_C);

    // PQ = X2 @ [edge_W halves]  -> [N,100]
    gemm_kernel<100, false, false, false><<<gemm_blocks, 256, 0, stream>>>(X0, nullptr, BPQ, nullptr, PQ, N_NODES_C);

    long ethreads = (long)N_EDGES_C * 13;   // 4-wide quads: 13 units per edge
    edge_out_kernel<<<(int)((ethreads + 255) / 256), 256, 0, stream>>>(FLAG, ei, PQ, edge_b, d_out);

    motif_kernel<<<N_CENTER_C, D_C, 0, stream>>>(FLAG, center, (const bf16*)X0, motif_W, motif_b, d_out);
    nodec_kernel<<<(N_NONMOL_C * 15 + 255) / 256, 256, 0, stream>>>(FLAG, nonmol, (const bf16*)X0, nodec_W, nodec_b, d_out);
    binary_kernel<<<(N_NODES_C * 64 + 255) / 256, 256, 0, stream>>>(FLAG, (const bf16*)X0, bin_W, bin_b, d_out);
}

// Round 18
// 686.123 us; speedup vs baseline: 1.0161x; 1.0161x over previous
//
#include <hip/hip_runtime.h>
#include <hip/hip_bf16.h>
#include <math.h>

typedef __hip_bfloat16 bf16;
typedef __attribute__((ext_vector_type(8))) short short8;
typedef __attribute__((ext_vector_type(4))) float float4v;
typedef __attribute__((ext_vector_type(2))) float float2v;
typedef __attribute__((ext_vector_type(2))) unsigned short ushort2v;
typedef __attribute__((ext_vector_type(4))) unsigned short ushort4v;

#define N_NODES_C 100000
#define N_EDGES_C 600000
#define N_CENTER_C 512
#define N_NONMOL_C 20000
#define N_REL_C 50
#define D_C 128
#define N_MOTIF_C 85

// element offsets into d_out (dtype-independent)
#define EO_EDGE  0L
#define EO_MOTIF 30000000L
#define EO_NODEC 30043520L
#define EO_BIN   30343520L

// byte offsets of scratch inside d_out (dead before any output is written;
// edge_out (first writer of d_out[0..60MB)) runs after all scratch consumers)
#define XA_OFF   0L
#define ET_OFF   51200000L
#define WT0_OFF  51225600L
#define WT1_OFF  51258368L
#define WT2_OFF  51291136L
#define BPQ_OFF  51323904L
#define LB_OFF   51352576L
#define B1_OFF   51353088L
#define B2_OFF   51353600L
#define OFFS_OFF 51354112L
#define BSUM_OFF 51755680L
#define SSRC_OFF 51757248L
#define SREL_OFF 54157248L
#define SDST_OFF 56557248L
#define NLO_OFF  58957248L
// NLO: (18750+1) ints = 75,004 B -> ends 59,032,252 < 60,887,040 (min d_out, bf16)

#define EPW_C 32                         // edge-window per wave (divides N_EDGES_C)
#define NW_C (N_EDGES_C / EPW_C)         // 18750 waves

__device__ __forceinline__ float b2f(bf16 v) { return __bfloat162float(v); }
__device__ __forceinline__ float bits2f(unsigned short s) {
    unsigned u = ((unsigned)s) << 16; float f; __builtin_memcpy(&f, &u, 4); return f;
}
__device__ __forceinline__ unsigned short f2bits(float f) {
    bf16 h = __float2bfloat16(f); unsigned short s; __builtin_memcpy(&s, &h, 2); return s;
}
__device__ __forceinline__ float ldf(const void* p, size_t i, int isbf) {
    return isbf ? __bfloat162float(((const bf16*)p)[i]) : ((const float*)p)[i];
}
// non-temporal final-output store (neutral on perf per round-12 A/B; harmless)
__device__ __forceinline__ void stout_nt(void* p, size_t i, int isbf, float v) {
    if (isbf) __builtin_nontemporal_store(f2bits(v), (unsigned short*)p + i);
    else      __builtin_nontemporal_store(v, (float*)p + i);
}

// ---- dtype probe ----
__global__ void probe_kernel(const void* __restrict__ table, int* __restrict__ flag) {
    __shared__ int bad[256];
    int t = threadIdx.x;
    const bf16* p = (const bf16*)table;
    int cnt = 0;
    for (int i = 0; i < 64; i++) {
        float v = __bfloat162float(p[t * 64 + i]);
        if (!isfinite(v) || fabsf(v) > 1000.0f) cnt++;
    }
    bad[t] = cnt;
    __syncthreads();
    for (int s = 128; s > 0; s >>= 1) {
        if (t < s) bad[t] += bad[t + s];
        __syncthreads();
    }
    if (t == 0) *flag = (bad[0] == 0) ? 1 : 0;   // 1 = bf16, 0 = fp32
}

// ---- prepack: WT[n][k] = W[k][n] (bf16), BPQ[j][k] from edge_W, biases fp32 ----
__global__ void prepack_kernel(const int* __restrict__ flag,
                               const void* __restrict__ linW, const void* __restrict__ w1,
                               const void* __restrict__ w2, const void* __restrict__ edgeW,
                               const void* __restrict__ linb, const void* __restrict__ bb1,
                               const void* __restrict__ bb2,
                               unsigned short* __restrict__ WT0, unsigned short* __restrict__ WT1,
                               unsigned short* __restrict__ WT2, unsigned short* __restrict__ BPQ,
                               float* __restrict__ LB, float* __restrict__ B1p, float* __restrict__ B2p) {
    int isbf = *flag;
    int g = blockIdx.x * 256 + threadIdx.x;
    if (g < 3 * 16384) {
        int w = g / 16384, i = g % 16384;
        int n = i >> 7, k = i & 127;
        const void* src = (w == 0) ? linW : (w == 1) ? w1 : w2;
        unsigned short* dst = (w == 0) ? WT0 : (w == 1) ? WT1 : WT2;
        dst[i] = f2bits(ldf(src, (size_t)k * 128 + n, isbf));
    } else if (g < 3 * 16384 + 112 * 128) {
        int i = g - 3 * 16384;
        int j = i >> 7, k = i & 127;
        float v = 0.0f;
        if (j < 50)       v = ldf(edgeW, (size_t)k * 50 + j, isbf);
        else if (j < 100) v = ldf(edgeW, (size_t)(128 + k) * 50 + (j - 50), isbf);
        BPQ[i] = f2bits(v);
    } else if (g < 3 * 16384 + 112 * 128 + 3 * 128) {
        int i = g - (3 * 16384 + 112 * 128);
        int w = i >> 7, n = i & 127;
        const void* src = (w == 0) ? linb : (w == 1) ? bb1 : bb2;
        float* dst = (w == 0) ? LB : (w == 1) ? B1p : B2p;
        dst[n] = ldf(src, n, isbf);
    }
}

// ---- ET (50 rows only): relu(l2norm(rel_emb) @ lin_W + lin_b) fp32 ----
__global__ void et_kernel(const int* __restrict__ flag,
                          const void* __restrict__ table,
                          const void* __restrict__ W,
                          const void* __restrict__ bias,
                          float* __restrict__ out) {
    int isbf = *flag;
    int row = blockIdx.x;
    int t = threadIdx.x;
    float v = ldf(table, (size_t)row * D_C + t, isbf);
    __shared__ float sv[D_C];
    __shared__ float red[D_C];
    red[t] = v * v;
    __syncthreads();
    for (int s = 64; s > 0; s >>= 1) {
        if (t < s) red[t] += red[t + s];
        __syncthreads();
    }
    float nrm = fmaxf(sqrtf(red[0]), 1e-12f);
    sv[t] = v / nrm;
    __syncthreads();
    float acc = ldf(bias, t, isbf);
    for (int k = 0; k < D_C; k++) acc = fmaf(sv[k], ldf(W, k * D_C + t, isbf), acc);
    out[(size_t)row * D_C + t] = fmaxf(acc, 0.0f);
}

// ---- normalize: one wave per row, 2 elems/lane ----
__global__ void normalize_kernel(const int* __restrict__ flag,
                                 const int* __restrict__ ids,
                                 const void* __restrict__ table,
                                 unsigned short* __restrict__ out) {
    int w = (int)((blockIdx.x * (long)blockDim.x + threadIdx.x) >> 6);
    int lane = threadIdx.x & 63;
    if (w >= N_NODES_C) return;
    int isbf = *flag;
    int id = ids[w];
    float v0, v1;
    if (isbf) {
        const unsigned short* p = (const unsigned short*)table + (size_t)id * D_C + lane * 2;
        ushort2 u = *(const ushort2*)p;
        v0 = bits2f(u.x); v1 = bits2f(u.y);
    } else {
        const float* p = (const float*)table + (size_t)id * D_C + lane * 2;
        float2 f = *(const float2*)p;
        v0 = f.x; v1 = f.y;
    }
    float ss = v0 * v0 + v1 * v1;
#pragma unroll
    for (int o = 32; o > 0; o >>= 1) ss += __shfl_down(ss, o, 64);
    ss = __shfl(ss, 0, 64);
    float inv = 1.0f / fmaxf(sqrtf(ss), 1e-12f);
    ushort2 o2;
    o2.x = f2bits(v0 * inv);
    o2.y = f2bits(v1 * inv);
    *(ushort2*)(out + (size_t)w * D_C + lane * 2) = o2;
}

// ---- MFMA GEMM: Y[M,NOUT] = act((X[+AGG]) @ BT^T + bias), K=128 resident ----
template <int NOUT, bool RELU, bool ADD_AGG, bool HAS_BIAS>
__global__ __launch_bounds__(256, 2) void gemm_kernel(
        const unsigned short* __restrict__ X,   // [M,128] bf16 bits
        const float* __restrict__ AGG,          // [M,128] fp32 (or null)
        const unsigned short* __restrict__ BT,  // [NT*16,128] bf16 bits, row n holds W[:,n]
        const float* __restrict__ bias,         // [NOUT] fp32 (or null)
        unsigned short* __restrict__ Y,         // [M,NOUT] bf16 bits
        int M) {
    constexpr int NT = (NOUT + 15) / 16;
    __shared__ short Als[128 * 128];
    __shared__ short Bls[NT * 16 * 128];
    int t = threadIdx.x;
    int m0 = blockIdx.x * 128;

#pragma unroll
    for (int p = 0; p < 8; p++) {
        int lin = (p * 256 + t) * 8;
        int row = lin >> 7, col = lin & 127;
        int gr = m0 + row; if (gr >= M) gr = M - 1;
        short8 xv = *(const short8*)(X + (size_t)gr * 128 + col);
        if (ADD_AGG) {
            const float* ap = AGG + (size_t)gr * 128 + col;
            float4v a0 = *(const float4v*)ap;
            float4v a1 = *(const float4v*)(ap + 4);
            short8 r;
#pragma unroll
            for (int i = 0; i < 4; i++) r[i] = (short)f2bits(bits2f((unsigned short)xv[i]) + a0[i]);
#pragma unroll
            for (int i = 0; i < 4; i++) r[4 + i] = (short)f2bits(bits2f((unsigned short)xv[4 + i]) + a1[i]);
            xv = r;
        }
        *(short8*)&Als[lin] = xv;
    }
    constexpr int BELEMS = NT * 16 * 128;
#pragma unroll
    for (int p = 0; p * 2048 < BELEMS; p++) {
        int lin = (p * 256 + t) * 8;
        if (lin < BELEMS) *(short8*)&Bls[lin] = *(const short8*)(BT + lin);
    }
    __syncthreads();

    int wave = t >> 6, lane = t & 63;
    int quad = lane >> 4, lr = lane & 15;
    int wr0 = wave * 32;

    short8 afr[2][4];
#pragma unroll
    for (int mt = 0; mt < 2; mt++)
#pragma unroll
        for (int kk = 0; kk < 4; kk++)
            afr[mt][kk] = *(short8*)&Als[(wr0 + mt * 16 + lr) * 128 + kk * 32 + quad * 8];

#pragma unroll
    for (int nt = 0; nt < NT; nt++) {
        short8 bfr[4];
#pragma unroll
        for (int kk = 0; kk < 4; kk++)
            bfr[kk] = *(short8*)&Bls[(nt * 16 + lr) * 128 + kk * 32 + quad * 8];
        int col = nt * 16 + lr;
        float bs = 0.0f;
        if (HAS_BIAS) bs = bias[col];
#pragma unroll
        for (int mt = 0; mt < 2; mt++) {
            float4v acc = {0.0f, 0.0f, 0.0f, 0.0f};
#pragma unroll
            for (int kk = 0; kk < 4; kk++)
                acc = __builtin_amdgcn_mfma_f32_16x16x32_bf16(afr[mt][kk], bfr[kk], acc, 0, 0, 0);
            int rbase = m0 + wr0 + mt * 16 + quad * 4;
#pragma unroll
            for (int r = 0; r < 4; r++) {
                int row = rbase + r;
                float v = acc[r] + bs;
                if (RELU) v = fmaxf(v, 0.0f);
                if (row < M && ((NOUT & 15) == 0 || col < NOUT))
                    Y[(size_t)row * NOUT + col] = f2bits(v);
            }
        }
    }
}

// ================= counting sort of edges by dst =================
__global__ void hist_kernel(const int* __restrict__ ei, int* __restrict__ cnt) {
    int e = blockIdx.x * 256 + threadIdx.x;
    if (e < N_EDGES_C) atomicAdd(&cnt[ei[N_EDGES_C + e]], 1);
}

// in-place: cnt -> exclusive-scan-within-block; bsum[b] = block total
__global__ void scan1_kernel(int* __restrict__ cnt, int* __restrict__ bsum) {
    __shared__ int s[256];
    int t = threadIdx.x;
    int idx = blockIdx.x * 256 + t;
    int v = (idx < N_NODES_C) ? cnt[idx] : 0;
    s[t] = v;
    __syncthreads();
    for (int o = 1; o < 256; o <<= 1) {
        int u = (t >= o) ? s[t - o] : 0;
        __syncthreads();
        s[t] += u;
        __syncthreads();
    }
    if (idx < N_NODES_C) cnt[idx] = s[t] - v;     // exclusive within block
    if (t == 255) bsum[blockIdx.x] = s[255];      // block total
}

// single block: bsum -> exclusive scan (NB=391 <= 512)
__global__ void scan2_kernel(int* __restrict__ bsum, int nb) {
    __shared__ int s[512];
    int t = threadIdx.x;
    int v = (t < nb) ? bsum[t] : 0;
    s[t] = v;
    __syncthreads();
    for (int o = 1; o < 512; o <<= 1) {
        int u = (t >= o) ? s[t - o] : 0;
        __syncthreads();
        s[t] += u;
        __syncthreads();
    }
    if (t < nb) bsum[t] = s[t] - v;               // exclusive
}

__global__ void scan3_kernel(int* __restrict__ cnt, const int* __restrict__ bsum) {
    int idx = blockIdx.x * 256 + threadIdx.x;
    if (idx < N_NODES_C) cnt[idx] += bsum[blockIdx.x];
}

// place edges; after this, offs[n] = end of segment n (start = offs[n-1], offs[-1]=0)
__global__ void sort_scatter_kernel(const int* __restrict__ ei, const int* __restrict__ rel,
                                    int* __restrict__ offs,
                                    int* __restrict__ ssrc, int* __restrict__ srel,
                                    int* __restrict__ sdst) {
    int e = blockIdx.x * 256 + threadIdx.x;
    if (e >= N_EDGES_C) return;
    int dst = ei[N_EDGES_C + e];
    int pos = atomicAdd(&offs[dst], 1);
    ssrc[pos] = ei[e];
    srel[pos] = rel[e];
    sdst[pos] = dst;
}

// ---- wave partition: NLO[w] = first node n with seg_start(n) >= w*EPW ----
// seg_start(n) = offs[n-1] (offs holds segment ENDS after sort_scatter).
// NLO[NW] = N. Node ranges [NLO[w], NLO[w+1]) partition [0,N): each node has
// exactly one owner wave -> gather needs NO atomics and can write XA directly.
__global__ void wave_part_kernel(const int* __restrict__ offs, int* __restrict__ nlo) {
    int w = blockIdx.x * 256 + threadIdx.x;
    if (w > NW_C) return;
    if (w == NW_C) { nlo[w] = N_NODES_C; return; }
    int target = w * EPW_C;
    int lo = 0, hi = N_NODES_C;
    while (lo < hi) {
        int mid = (lo + hi) >> 1;
        int s = (mid == 0) ? 0 : offs[mid - 1];
        if (s >= target) hi = mid; else lo = mid + 1;
    }
    nlo[w] = lo;
}

// ---- fused gather: XA[n] = bf16(x[n] + sum over n's in-edges relu(x[src]+ET[rel])) ----
// Wave w owns nodes [NLO[w], NLO[w+1]); processes its full contiguous edge range
// (segments wholly owned -> every write is a plain store; no memset, no atomics).
// Zero-degree nodes in range get XA = x. GEMM then reads XA with ADD_AGG=false.
__global__ __launch_bounds__(256) void gather_fuse_kernel(
        const unsigned short* __restrict__ x,
        const int* __restrict__ offs,
        const int* __restrict__ ssrc, const int* __restrict__ srel,
        const int* __restrict__ sdst,
        const int* __restrict__ nlo_arr,
        const float* __restrict__ etab,
        unsigned short* __restrict__ xa) {
    int w = (int)((blockIdx.x * 256u + threadIdx.x) >> 6);
    int lane = threadIdx.x & 63;
    if (w >= NW_C) return;
    int nlo = nlo_arr[w];
    int nhi = nlo_arr[w + 1];
    if (nlo >= nhi) return;            // window inside a giant segment: no owned nodes
    int estart = (nlo == 0) ? 0 : offs[nlo - 1];
    int eend = offs[nhi - 1];

    float a0 = 0.0f, a1 = 0.0f;
    int cur = (estart < eend) ? sdst[estart] : -1;

    for (int e = estart; e < eend; e += 4) {
        int s_[4], r_[4], d_[4];
        ushort2 uu[4];
        float2 tt[4];
#pragma unroll
        for (int j = 0; j < 4; j++) {
            int idx = (e + j < eend) ? (e + j) : (eend - 1);   // clamp tail (guarded below)
            s_[j] = ssrc[idx]; r_[j] = srel[idx]; d_[j] = sdst[idx];
        }
        // issue all x-row + etab loads before consuming: MLP=4
#pragma unroll
        for (int j = 0; j < 4; j++) uu[j] = *(const ushort2*)(x + (size_t)s_[j] * D_C + lane * 2);
#pragma unroll
        for (int j = 0; j < 4; j++) tt[j] = *(const float2*)(etab + (size_t)r_[j] * D_C + lane * 2);
#pragma unroll
        for (int j = 0; j < 4; j++) {
            if (e + j < eend) {
                if (d_[j] != cur) {
                    ushort2 xr = *(const ushort2*)(x + (size_t)cur * D_C + lane * 2);
                    ushort2 o;
                    o.x = f2bits(bits2f(xr.x) + a0);
                    o.y = f2bits(bits2f(xr.y) + a1);
                    *(ushort2*)(xa + (size_t)cur * D_C + lane * 2) = o;
                    a0 = 0.0f; a1 = 0.0f; cur = d_[j];
                }
                a0 += fmaxf(bits2f(uu[j].x) + tt[j].x, 0.0f);
                a1 += fmaxf(bits2f(uu[j].y) + tt[j].y, 0.0f);
            }
        }
    }
    if (cur >= 0) {                    // final flush (always a plain store)
        ushort2 xr = *(const ushort2*)(x + (size_t)cur * D_C + lane * 2);
        ushort2 o;
        o.x = f2bits(bits2f(xr.x) + a0);
        o.y = f2bits(bits2f(xr.y) + a1);
        *(ushort2*)(xa + (size_t)cur * D_C + lane * 2) = o;
    }
    // zero-degree nodes in [nlo, nhi): XA = x
    int prev = estart;
    for (int nn = nlo; nn < nhi; nn++) {
        int se = offs[nn];
        if (se == prev) {
            *(ushort2*)(xa + (size_t)nn * D_C + lane * 2) =
                *(const ushort2*)(x + (size_t)nn * D_C + lane * 2);
        }
        prev = se;
    }
}

// ---- edge head, 4-wide quads: 13 units/edge (12 quads + 1 pair) ----
__global__ void edge_out_kernel(const int* __restrict__ flag,
                                const int* __restrict__ ei,
                                const unsigned short* __restrict__ PQ,
                                const void* __restrict__ eb,
                                void* __restrict__ out) {
    int isbf = *flag;
    long g = (long)blockIdx.x * blockDim.x + threadIdx.x;
    if (g >= (long)N_EDGES_C * 13) return;
    int e = (int)(g / 13);
    int jq = (int)(g - (long)e * 13);
    int src = ei[e];
    int dst = ei[N_EDGES_C + e];
    if (jq < 12) {
        int j = jq * 4;
        ushort4v us = *(const ushort4v*)(PQ + (size_t)src * 100 + j);
        ushort2v ud0 = *(const ushort2v*)(PQ + (size_t)dst * 100 + 50 + j);
        ushort2v ud1 = *(const ushort2v*)(PQ + (size_t)dst * 100 + 50 + j + 2);
        float v0 = bits2f(us.x) + bits2f(ud0.x) + ldf(eb, j, isbf);
        float v1 = bits2f(us.y) + bits2f(ud0.y) + ldf(eb, j + 1, isbf);
        float v2 = bits2f(us.z) + bits2f(ud1.x) + ldf(eb, j + 2, isbf);
        float v3 = bits2f(us.w) + bits2f(ud1.y) + ldf(eb, j + 3, isbf);
        if (isbf) {
            ushort2v o0; o0.x = f2bits(v0); o0.y = f2bits(v1);
            ushort2v o1; o1.x = f2bits(v2); o1.y = f2bits(v3);
            unsigned short* ob = (unsigned short*)out + EO_EDGE + (size_t)e * 50 + j;
            __builtin_nontemporal_store(o0, (ushort2v*)ob);
            __builtin_nontemporal_store(o1, (ushort2v*)(ob + 2));
        } else {
            float2v o0; o0.x = v0; o0.y = v1;
            float2v o1; o1.x = v2; o1.y = v3;
            float* ob = (float*)out + EO_EDGE + (size_t)e * 50 + j;
            __builtin_nontemporal_store(o0, (float2v*)ob);
            __builtin_nontemporal_store(o1, (float2v*)(ob + 2));
        }
    } else {
        int j = 48;
        ushort2v us = *(const ushort2v*)(PQ + (size_t)src * 100 + j);
        ushort2v ud = *(const ushort2v*)(PQ + (size_t)dst * 100 + 50 + j);
        float v0 = bits2f(us.x) + bits2f(ud.x) + ldf(eb, j, isbf);
        float v1 = bits2f(us.y) + bits2f(ud.y) + ldf(eb, j + 1, isbf);
        if (isbf) {
            ushort2v o; o.x = f2bits(v0); o.y = f2bits(v1);
            __builtin_nontemporal_store(o, (ushort2v*)((unsigned short*)out + EO_EDGE + (size_t)e * 50 + j));
        } else {
            float2v o; o.x = v0; o.y = v1;
            __builtin_nontemporal_store(o, (float2v*)((float*)out + EO_EDGE + (size_t)e * 50 + j));
        }
    }
}

__global__ void motif_kernel(const int* __restrict__ flag,
                             const int* __restrict__ cidx,
                             const bf16* __restrict__ x,
                             const void* __restrict__ W,
                             const void* __restrict__ bias,
                             void* __restrict__ out) {
    int isbf = *flag;
    int row = blockIdx.x;
    int t = threadIdx.x;
    __shared__ float sv[D_C];
    int id = cidx[row];
    sv[t] = b2f(x[(size_t)id * D_C + t]);
    __syncthreads();
    if (t < N_MOTIF_C) {
        float acc = ldf(bias, t, isbf);
        for (int k = 0; k < D_C; k++) acc = fmaf(sv[k], ldf(W, k * N_MOTIF_C + t, isbf), acc);
        stout_nt(out, EO_MOTIF + (size_t)row * N_MOTIF_C + t, isbf, acc);
    }
}

__global__ void nodec_kernel(const int* __restrict__ flag,
                             const int* __restrict__ nidx,
                             const bf16* __restrict__ x,
                             const void* __restrict__ W,
                             const void* __restrict__ bias,
                             void* __restrict__ out) {
    int isbf = *flag;
    int g = blockIdx.x * blockDim.x + threadIdx.x;
    if (g >= N_NONMOL_C * 15) return;
    int row = g / 15;
    int j = g - row * 15;
    int id = nidx[row];
    float acc = ldf(bias, j, isbf);
    for (int k = 0; k < D_C; k++) acc = fmaf(b2f(x[(size_t)id * D_C + k]), ldf(W, k * 15 + j, isbf), acc);
    stout_nt(out, EO_NODEC + g, isbf, acc);
}

__global__ void binary_kernel(const int* __restrict__ flag,
                              const bf16* __restrict__ x,
                              const void* __restrict__ W,
                              const void* __restrict__ bias,
                              void* __restrict__ out) {
    int isbf = *flag;
    int g = blockIdx.x * blockDim.x + threadIdx.x;
    int row = g >> 6;
    int lane = threadIdx.x & 63;
    if (row >= N_NODES_C) return;
    float a = b2f(x[(size_t)row * D_C + lane]) * ldf(W, lane, isbf) +
              b2f(x[(size_t)row * D_C + 64 + lane]) * ldf(W, 64 + lane, isbf);
#pragma unroll
    for (int off = 32; off > 0; off >>= 1) a += __shfl_down(a, off, 64);
    if (lane == 0) stout_nt(out, EO_BIN + row, isbf, a + ldf(bias, 0, isbf));
}

extern "C" void kernel_launch(void* const* d_in, const int* in_sizes, int n_in,
                              void* d_out, int out_size, void* d_ws, size_t ws_size,
                              hipStream_t stream) {
    const int* node_ids = (const int*)d_in[0];
    const int* rel_ids  = (const int*)d_in[1];
    const int* center   = (const int*)d_in[2];
    const int* nonmol   = (const int*)d_in[3];
    const int* ei       = (const int*)d_in[4];
    const void* node_emb = d_in[5];
    const void* rel_emb  = d_in[6];
    const void* lin_W = d_in[7];
    const void* lin_b = d_in[8];
    const void* W1 = d_in[9];
    const void* b1 = d_in[10];
    const void* W2 = d_in[11];
    const void* b2 = d_in[12];
    const void* edge_W = d_in[13];
    const void* edge_b = d_in[14];
    const void* motif_W = d_in[15];
    const void* motif_b = d_in[16];
    const void* nodec_W = d_in[17];
    const void* nodec_b = d_in[18];
    const void* bin_W = d_in[19];
    const void* bin_b = d_in[20];

    // ws: X0 [0,25.6MB), X1 [25.6,51.2MB), FLAG (4B)
    char* wsb = (char*)d_ws;
    unsigned short* X0 = (unsigned short*)wsb;
    unsigned short* X1 = (unsigned short*)(wsb + (size_t)N_NODES_C * D_C * 2);
    int* FLAG = (int*)(wsb + (size_t)2 * N_NODES_C * D_C * 2);
    unsigned short* PQ = X1;

    // scratch carved from dead d_out space
    char* ob = (char*)d_out;
    unsigned short* XA = (unsigned short*)(ob + XA_OFF);
    float* ET  = (float*)(ob + ET_OFF);
    unsigned short* WT0 = (unsigned short*)(ob + WT0_OFF);
    unsigned short* WT1 = (unsigned short*)(ob + WT1_OFF);
    unsigned short* WT2 = (unsigned short*)(ob + WT2_OFF);
    unsigned short* BPQ = (unsigned short*)(ob + BPQ_OFF);
    float* LB  = (float*)(ob + LB_OFF);
    float* B1p = (float*)(ob + B1_OFF);
    float* B2p = (float*)(ob + B2_OFF);
    int* OFFS = (int*)(ob + OFFS_OFF);
    int* BSUM = (int*)(ob + BSUM_OFF);
    int* SSRC = (int*)(ob + SSRC_OFF);
    int* SREL = (int*)(ob + SREL_OFF);
    int* SDST = (int*)(ob + SDST_OFF);
    int* NLO  = (int*)(ob + NLO_OFF);

    const int gemm_blocks = (N_NODES_C + 127) / 128;   // 782
    const int nscan = (N_NODES_C + 255) / 256;         // 391
    const int eblocks = (N_EDGES_C + 255) / 256;
    const int g2_blocks = (NW_C + 3) / 4;              // 4 waves/block

    probe_kernel<<<1, 256, 0, stream>>>(node_emb, FLAG);
    prepack_kernel<<<250, 256, 0, stream>>>(FLAG, lin_W, W1, W2, edge_W, lin_b, b1, b2,
                                            WT0, WT1, WT2, BPQ, LB, B1p, B2p);
    et_kernel<<<N_REL_C, D_C, 0, stream>>>(FLAG, rel_emb, lin_W, lin_b, ET);

    // ---- counting sort of edges by dst (reused by both convs) ----
    hipMemsetAsync(OFFS, 0, N_NODES_C * sizeof(int), stream);
    hist_kernel<<<eblocks, 256, 0, stream>>>(ei, OFFS);
    scan1_kernel<<<nscan, 256, 0, stream>>>(OFFS, BSUM);
    scan2_kernel<<<1, 512, 0, stream>>>(BSUM, nscan);
    scan3_kernel<<<nscan, 256, 0, stream>>>(OFFS, BSUM);
    sort_scatter_kernel<<<eblocks, 256, 0, stream>>>(ei, rel_ids, OFFS, SSRC, SREL, SDST);
    wave_part_kernel<<<(NW_C + 1 + 255) / 256, 256, 0, stream>>>(OFFS, NLO);

    // X0 = l2norm(node_emb[node_ids]), then in-place X0 = relu(X0 @ lin_W + lin_b)
    normalize_kernel<<<(N_NODES_C * 64 + 255) / 256, 256, 0, stream>>>(FLAG, node_ids, node_emb, X0);
    gemm_kernel<128, true, false, true><<<gemm_blocks, 256, 0, stream>>>(X0, nullptr, WT0, LB, X0, N_NODES_C);

    // GINE conv 1: XA = X0 + agg(X0);  X1 = relu(XA @ W1 + b1)
    gather_fuse_kernel<<<g2_blocks, 256, 0, stream>>>(X0, OFFS, SSRC, SREL, SDST, NLO, ET, XA);
    gemm_kernel<128, true, false, true><<<gemm_blocks, 256, 0, stream>>>(XA, nullptr, WT1, B1p, X1, N_NODES_C);

    // GINE conv 2: XA = X1 + agg(X1);  X2(=X0 slot) = XA @ W2 + b2
    gather_fuse_kernel<<<g2_blocks, 256, 0, stream>>>(X1, OFFS, SSRC, SREL, SDST, NLO, ET, XA);
    gemm_kernel<128, false, false, true><<<gemm_blocks, 256, 0, stream>>>(XA, nullptr, WT2, B2p, X0, N_NODES_C);

    // PQ = X2 @ [edge_W halves]  -> [N,100]
    gemm_kernel<100, false, false, false><<<gemm_blocks, 256, 0, stream>>>(X0, nullptr, BPQ, nullptr, PQ, N_NODES_C);

    long ethreads = (long)N_EDGES_C * 13;   // 4-wide quads: 13 units per edge
    edge_out_kernel<<<(int)((ethreads + 255) / 256), 256, 0, stream>>>(FLAG, ei, PQ, edge_b, d_out);

    motif_kernel<<<N_CENTER_C, D_C, 0, stream>>>(FLAG, center, (const bf16*)X0, motif_W, motif_b, d_out);
    nodec_kernel<<<(N_NONMOL_C * 15 + 255) / 256, 256, 0, stream>>>(FLAG, nonmol, (const bf16*)X0, nodec_W, nodec_b, d_out);
    binary_kernel<<<(N_NODES_C * 64 + 255) / 256, 256, 0, stream>>>(FLAG, (const bf16*)X0, bin_W, bin_b, d_out);
}

// Round 19
// 666.897 us; speedup vs baseline: 1.0454x; 1.0288x over previous
//
#include <hip/hip_runtime.h>
#include <hip/hip_bf16.h>
#include <math.h>

typedef __hip_bfloat16 bf16;
typedef __attribute__((ext_vector_type(8))) short short8;
typedef __attribute__((ext_vector_type(4))) float float4v;
typedef __attribute__((ext_vector_type(2))) float float2v;
typedef __attribute__((ext_vector_type(2))) unsigned short ushort2v;
typedef __attribute__((ext_vector_type(4))) unsigned short ushort4v;

#define N_NODES_C 100000
#define N_EDGES_C 600000
#define N_CENTER_C 512
#define N_NONMOL_C 20000
#define N_REL_C 50
#define D_C 128
#define N_MOTIF_C 85

// element offsets into d_out (dtype-independent)
#define EO_EDGE  0L
#define EO_MOTIF 30000000L
#define EO_NODEC 30043520L
#define EO_BIN   30343520L

// byte offsets of scratch inside d_out (dead before any output is written;
// edge_out (first writer of d_out[0..60MB)) runs after all scratch consumers)
#define XA_OFF   0L
#define ET_OFF   51200000L
#define WT0_OFF  51225600L
#define WT1_OFF  51258368L
#define WT2_OFF  51291136L
#define BPQ_OFF  51323904L
#define LB_OFF   51352576L
#define B1_OFF   51353088L
#define B2_OFF   51353600L
#define OFFS_OFF 51354112L
#define BSUM_OFF 51755680L
#define SSRC_OFF 51757248L
#define SREL_OFF 54157248L
#define SDST_OFF 56557248L
#define NLO_OFF  58957248L
// NLO: (18750+1) ints = 75,004 B -> ends 59,032,252 < 60,887,040 (min d_out, bf16)

#define EPW_C 32                         // edge-window per wave (divides N_EDGES_C)
#define NW_C (N_EDGES_C / EPW_C)         // 18750 waves

__device__ __forceinline__ float b2f(bf16 v) { return __bfloat162float(v); }
__device__ __forceinline__ float bits2f(unsigned short s) {
    unsigned u = ((unsigned)s) << 16; float f; __builtin_memcpy(&f, &u, 4); return f;
}
__device__ __forceinline__ unsigned short f2bits(float f) {
    bf16 h = __float2bfloat16(f); unsigned short s; __builtin_memcpy(&s, &h, 2); return s;
}
__device__ __forceinline__ float ldf(const void* p, size_t i, int isbf) {
    return isbf ? __bfloat162float(((const bf16*)p)[i]) : ((const float*)p)[i];
}
// non-temporal final-output store (neutral on perf per round-12 A/B; harmless)
__device__ __forceinline__ void stout_nt(void* p, size_t i, int isbf, float v) {
    if (isbf) __builtin_nontemporal_store(f2bits(v), (unsigned short*)p + i);
    else      __builtin_nontemporal_store(v, (float*)p + i);
}

// ---- dtype probe ----
__global__ void probe_kernel(const void* __restrict__ table, int* __restrict__ flag) {
    __shared__ int bad[256];
    int t = threadIdx.x;
    const bf16* p = (const bf16*)table;
    int cnt = 0;
    for (int i = 0; i < 64; i++) {
        float v = __bfloat162float(p[t * 64 + i]);
        if (!isfinite(v) || fabsf(v) > 1000.0f) cnt++;
    }
    bad[t] = cnt;
    __syncthreads();
    for (int s = 128; s > 0; s >>= 1) {
        if (t < s) bad[t] += bad[t + s];
        __syncthreads();
    }
    if (t == 0) *flag = (bad[0] == 0) ? 1 : 0;   // 1 = bf16, 0 = fp32
}

// ---- prepack: WT[n][k] = W[k][n] (bf16), BPQ[j][k] from edge_W, biases fp32 ----
__global__ void prepack_kernel(const int* __restrict__ flag,
                               const void* __restrict__ linW, const void* __restrict__ w1,
                               const void* __restrict__ w2, const void* __restrict__ edgeW,
                               const void* __restrict__ linb, const void* __restrict__ bb1,
                               const void* __restrict__ bb2,
                               unsigned short* __restrict__ WT0, unsigned short* __restrict__ WT1,
                               unsigned short* __restrict__ WT2, unsigned short* __restrict__ BPQ,
                               float* __restrict__ LB, float* __restrict__ B1p, float* __restrict__ B2p) {
    int isbf = *flag;
    int g = blockIdx.x * 256 + threadIdx.x;
    if (g < 3 * 16384) {
        int w = g / 16384, i = g % 16384;
        int n = i >> 7, k = i & 127;
        const void* src = (w == 0) ? linW : (w == 1) ? w1 : w2;
        unsigned short* dst = (w == 0) ? WT0 : (w == 1) ? WT1 : WT2;
        dst[i] = f2bits(ldf(src, (size_t)k * 128 + n, isbf));
    } else if (g < 3 * 16384 + 112 * 128) {
        int i = g - 3 * 16384;
        int j = i >> 7, k = i & 127;
        float v = 0.0f;
        if (j < 50)       v = ldf(edgeW, (size_t)k * 50 + j, isbf);
        else if (j < 100) v = ldf(edgeW, (size_t)(128 + k) * 50 + (j - 50), isbf);
        BPQ[i] = f2bits(v);
    } else if (g < 3 * 16384 + 112 * 128 + 3 * 128) {
        int i = g - (3 * 16384 + 112 * 128);
        int w = i >> 7, n = i & 127;
        const void* src = (w == 0) ? linb : (w == 1) ? bb1 : bb2;
        float* dst = (w == 0) ? LB : (w == 1) ? B1p : B2p;
        dst[n] = ldf(src, n, isbf);
    }
}

// ---- ET (50 rows only): relu(l2norm(rel_emb) @ lin_W + lin_b) fp32 ----
__global__ void et_kernel(const int* __restrict__ flag,
                          const void* __restrict__ table,
                          const void* __restrict__ W,
                          const void* __restrict__ bias,
                          float* __restrict__ out) {
    int isbf = *flag;
    int row = blockIdx.x;
    int t = threadIdx.x;
    float v = ldf(table, (size_t)row * D_C + t, isbf);
    __shared__ float sv[D_C];
    __shared__ float red[D_C];
    red[t] = v * v;
    __syncthreads();
    for (int s = 64; s > 0; s >>= 1) {
        if (t < s) red[t] += red[t + s];
        __syncthreads();
    }
    float nrm = fmaxf(sqrtf(red[0]), 1e-12f);
    sv[t] = v / nrm;
    __syncthreads();
    float acc = ldf(bias, t, isbf);
    for (int k = 0; k < D_C; k++) acc = fmaf(sv[k], ldf(W, k * D_C + t, isbf), acc);
    out[(size_t)row * D_C + t] = fmaxf(acc, 0.0f);
}

// ---- fused GEMM0: X0 = relu(l2norm(emb[ids]) @ WT0^T + bias) ----
// A-stage gathers emb rows, computes per-row L2 norm in-block, writes
// normalized bf16 to Als from register-held raw values (no X-normalize pass).
__global__ __launch_bounds__(256, 2) void gemm0_norm_kernel(
        const int* __restrict__ flag,
        const int* __restrict__ ids,
        const void* __restrict__ emb,
        const unsigned short* __restrict__ BT,  // [128,128] bf16 bits
        const float* __restrict__ bias,         // [128] fp32
        unsigned short* __restrict__ Y,         // [M,128] bf16 bits
        int M) {
    __shared__ short Als[128 * 128];
    __shared__ short Bls[128 * 128];
    __shared__ float red[128][17];   // +1 pad: per-row 16 sumsq partials
    __shared__ float invn[128];
    int isbf = *flag;
    int t = threadIdx.x;
    int m0 = blockIdx.x * 128;

    float fv[8][8];
#pragma unroll
    for (int p = 0; p < 8; p++) {
        int lin = (p * 256 + t) * 8;
        int row = lin >> 7, col = lin & 127;
        int gr = m0 + row; if (gr >= M) gr = M - 1;
        int id = ids[gr];
        if (isbf) {
            short8 v = *(const short8*)((const unsigned short*)emb + (size_t)id * D_C + col);
#pragma unroll
            for (int i = 0; i < 8; i++) fv[p][i] = bits2f((unsigned short)v[i]);
        } else {
            const float* ep = (const float*)emb + (size_t)id * D_C + col;
            float4v a0 = *(const float4v*)ep;
            float4v a1 = *(const float4v*)(ep + 4);
#pragma unroll
            for (int i = 0; i < 4; i++) { fv[p][i] = a0[i]; fv[p][4 + i] = a1[i]; }
        }
        float ss = 0.0f;
#pragma unroll
        for (int i = 0; i < 8; i++) ss += fv[p][i] * fv[p][i];
        red[row][col >> 3] = ss;     // each (row,colgroup) has exactly one writer
    }
    __syncthreads();
    if (t < 128) {
        float ss = 0.0f;
#pragma unroll
        for (int cg = 0; cg < 16; cg++) ss += red[t][cg];
        invn[t] = 1.0f / fmaxf(sqrtf(ss), 1e-12f);
    }
    // stage B while norm finishes
    {
#pragma unroll
        for (int p = 0; p < 8; p++) {
            int lin = (p * 256 + t) * 8;
            *(short8*)&Bls[lin] = *(const short8*)(BT + lin);
        }
    }
    __syncthreads();
#pragma unroll
    for (int p = 0; p < 8; p++) {
        int lin = (p * 256 + t) * 8;
        int row = lin >> 7;
        float iv = invn[row];
        short8 xv;
#pragma unroll
        for (int i = 0; i < 8; i++) xv[i] = (short)f2bits(fv[p][i] * iv);
        *(short8*)&Als[lin] = xv;
    }
    __syncthreads();

    int wave = t >> 6, lane = t & 63;
    int quad = lane >> 4, lr = lane & 15;
    int wr0 = wave * 32;

    short8 afr[2][4];
#pragma unroll
    for (int mt = 0; mt < 2; mt++)
#pragma unroll
        for (int kk = 0; kk < 4; kk++)
            afr[mt][kk] = *(short8*)&Als[(wr0 + mt * 16 + lr) * 128 + kk * 32 + quad * 8];

#pragma unroll
    for (int nt = 0; nt < 8; nt++) {
        short8 bfr[4];
#pragma unroll
        for (int kk = 0; kk < 4; kk++)
            bfr[kk] = *(short8*)&Bls[(nt * 16 + lr) * 128 + kk * 32 + quad * 8];
        int col = nt * 16 + lr;
        float bs = bias[col];
#pragma unroll
        for (int mt = 0; mt < 2; mt++) {
            float4v acc = {0.0f, 0.0f, 0.0f, 0.0f};
#pragma unroll
            for (int kk = 0; kk < 4; kk++)
                acc = __builtin_amdgcn_mfma_f32_16x16x32_bf16(afr[mt][kk], bfr[kk], acc, 0, 0, 0);
            int rbase = m0 + wr0 + mt * 16 + quad * 4;
#pragma unroll
            for (int r = 0; r < 4; r++) {
                int row = rbase + r;
                float v = fmaxf(acc[r] + bs, 0.0f);
                if (row < M) Y[(size_t)row * 128 + col] = f2bits(v);
            }
        }
    }
}

// ---- MFMA GEMM: Y[M,NOUT] = act((X[+AGG]) @ BT^T + bias), K=128 resident ----
template <int NOUT, bool RELU, bool ADD_AGG, bool HAS_BIAS>
__global__ __launch_bounds__(256, 2) void gemm_kernel(
        const unsigned short* __restrict__ X,   // [M,128] bf16 bits
        const float* __restrict__ AGG,          // [M,128] fp32 (or null)
        const unsigned short* __restrict__ BT,  // [NT*16,128] bf16 bits, row n holds W[:,n]
        const float* __restrict__ bias,         // [NOUT] fp32 (or null)
        unsigned short* __restrict__ Y,         // [M,NOUT] bf16 bits
        int M) {
    constexpr int NT = (NOUT + 15) / 16;
    __shared__ short Als[128 * 128];
    __shared__ short Bls[NT * 16 * 128];
    int t = threadIdx.x;
    int m0 = blockIdx.x * 128;

#pragma unroll
    for (int p = 0; p < 8; p++) {
        int lin = (p * 256 + t) * 8;
        int row = lin >> 7, col = lin & 127;
        int gr = m0 + row; if (gr >= M) gr = M - 1;
        short8 xv = *(const short8*)(X + (size_t)gr * 128 + col);
        if (ADD_AGG) {
            const float* ap = AGG + (size_t)gr * 128 + col;
            float4v a0 = *(const float4v*)ap;
            float4v a1 = *(const float4v*)(ap + 4);
            short8 r;
#pragma unroll
            for (int i = 0; i < 4; i++) r[i] = (short)f2bits(bits2f((unsigned short)xv[i]) + a0[i]);
#pragma unroll
            for (int i = 0; i < 4; i++) r[4 + i] = (short)f2bits(bits2f((unsigned short)xv[4 + i]) + a1[i]);
            xv = r;
        }
        *(short8*)&Als[lin] = xv;
    }
    constexpr int BELEMS = NT * 16 * 128;
#pragma unroll
    for (int p = 0; p * 2048 < BELEMS; p++) {
        int lin = (p * 256 + t) * 8;
        if (lin < BELEMS) *(short8*)&Bls[lin] = *(const short8*)(BT + lin);
    }
    __syncthreads();

    int wave = t >> 6, lane = t & 63;
    int quad = lane >> 4, lr = lane & 15;
    int wr0 = wave * 32;

    short8 afr[2][4];
#pragma unroll
    for (int mt = 0; mt < 2; mt++)
#pragma unroll
        for (int kk = 0; kk < 4; kk++)
            afr[mt][kk] = *(short8*)&Als[(wr0 + mt * 16 + lr) * 128 + kk * 32 + quad * 8];

#pragma unroll
    for (int nt = 0; nt < NT; nt++) {
        short8 bfr[4];
#pragma unroll
        for (int kk = 0; kk < 4; kk++)
            bfr[kk] = *(short8*)&Bls[(nt * 16 + lr) * 128 + kk * 32 + quad * 8];
        int col = nt * 16 + lr;
        float bs = 0.0f;
        if (HAS_BIAS) bs = bias[col];
#pragma unroll
        for (int mt = 0; mt < 2; mt++) {
            float4v acc = {0.0f, 0.0f, 0.0f, 0.0f};
#pragma unroll
            for (int kk = 0; kk < 4; kk++)
                acc = __builtin_amdgcn_mfma_f32_16x16x32_bf16(afr[mt][kk], bfr[kk], acc, 0, 0, 0);
            int rbase = m0 + wr0 + mt * 16 + quad * 4;
#pragma unroll
            for (int r = 0; r < 4; r++) {
                int row = rbase + r;
                float v = acc[r] + bs;
                if (RELU) v = fmaxf(v, 0.0f);
                if (row < M && ((NOUT & 15) == 0 || col < NOUT))
                    Y[(size_t)row * NOUT + col] = f2bits(v);
            }
        }
    }
}

// ================= counting sort of edges by dst =================
__global__ void hist_kernel(const int* __restrict__ ei, int* __restrict__ cnt) {
    int e = blockIdx.x * 256 + threadIdx.x;
    if (e < N_EDGES_C) atomicAdd(&cnt[ei[N_EDGES_C + e]], 1);
}

// in-place: cnt -> exclusive-scan-within-block; bsum[b] = block total
__global__ void scan1_kernel(int* __restrict__ cnt, int* __restrict__ bsum) {
    __shared__ int s[256];
    int t = threadIdx.x;
    int idx = blockIdx.x * 256 + t;
    int v = (idx < N_NODES_C) ? cnt[idx] : 0;
    s[t] = v;
    __syncthreads();
    for (int o = 1; o < 256; o <<= 1) {
        int u = (t >= o) ? s[t - o] : 0;
        __syncthreads();
        s[t] += u;
        __syncthreads();
    }
    if (idx < N_NODES_C) cnt[idx] = s[t] - v;     // exclusive within block
    if (t == 255) bsum[blockIdx.x] = s[255];      // block total
}

// single block: bsum -> exclusive scan (NB=391 <= 512)
__global__ void scan2_kernel(int* __restrict__ bsum, int nb) {
    __shared__ int s[512];
    int t = threadIdx.x;
    int v = (t < nb) ? bsum[t] : 0;
    s[t] = v;
    __syncthreads();
    for (int o = 1; o < 512; o <<= 1) {
        int u = (t >= o) ? s[t - o] : 0;
        __syncthreads();
        s[t] += u;
        __syncthreads();
    }
    if (t < nb) bsum[t] = s[t] - v;               // exclusive
}

__global__ void scan3_kernel(int* __restrict__ cnt, const int* __restrict__ bsum) {
    int idx = blockIdx.x * 256 + threadIdx.x;
    if (idx < N_NODES_C) cnt[idx] += bsum[blockIdx.x];
}

// place edges; after this, offs[n] = end of segment n (start = offs[n-1], offs[-1]=0)
__global__ void sort_scatter_kernel(const int* __restrict__ ei, const int* __restrict__ rel,
                                    int* __restrict__ offs,
                                    int* __restrict__ ssrc, int* __restrict__ srel,
                                    int* __restrict__ sdst) {
    int e = blockIdx.x * 256 + threadIdx.x;
    if (e >= N_EDGES_C) return;
    int dst = ei[N_EDGES_C + e];
    int pos = atomicAdd(&offs[dst], 1);
    ssrc[pos] = ei[e];
    srel[pos] = rel[e];
    sdst[pos] = dst;
}

// ---- wave partition: NLO[w] = first node n with seg_start(n) >= w*EPW ----
__global__ void wave_part_kernel(const int* __restrict__ offs, int* __restrict__ nlo) {
    int w = blockIdx.x * 256 + threadIdx.x;
    if (w > NW_C) return;
    if (w == NW_C) { nlo[w] = N_NODES_C; return; }
    int target = w * EPW_C;
    int lo = 0, hi = N_NODES_C;
    while (lo < hi) {
        int mid = (lo + hi) >> 1;
        int s = (mid == 0) ? 0 : offs[mid - 1];
        if (s >= target) hi = mid; else lo = mid + 1;
    }
    nlo[w] = lo;
}

// ---- fused gather: XA[n] = bf16(x[n] + sum over n's in-edges relu(x[src]+ET[rel])) ----
__global__ __launch_bounds__(256) void gather_fuse_kernel(
        const unsigned short* __restrict__ x,
        const int* __restrict__ offs,
        const int* __restrict__ ssrc, const int* __restrict__ srel,
        const int* __restrict__ sdst,
        const int* __restrict__ nlo_arr,
        const float* __restrict__ etab,
        unsigned short* __restrict__ xa) {
    int w = (int)((blockIdx.x * 256u + threadIdx.x) >> 6);
    int lane = threadIdx.x & 63;
    if (w >= NW_C) return;
    int nlo = nlo_arr[w];
    int nhi = nlo_arr[w + 1];
    if (nlo >= nhi) return;            // window inside a giant segment: no owned nodes
    int estart = (nlo == 0) ? 0 : offs[nlo - 1];
    int eend = offs[nhi - 1];

    float a0 = 0.0f, a1 = 0.0f;
    int cur = (estart < eend) ? sdst[estart] : -1;

    for (int e = estart; e < eend; e += 4) {
        int s_[4], r_[4], d_[4];
        ushort2 uu[4];
        float2 tt[4];
#pragma unroll
        for (int j = 0; j < 4; j++) {
            int idx = (e + j < eend) ? (e + j) : (eend - 1);   // clamp tail (guarded below)
            s_[j] = ssrc[idx]; r_[j] = srel[idx]; d_[j] = sdst[idx];
        }
        // issue all x-row + etab loads before consuming: MLP=4
#pragma unroll
        for (int j = 0; j < 4; j++) uu[j] = *(const ushort2*)(x + (size_t)s_[j] * D_C + lane * 2);
#pragma unroll
        for (int j = 0; j < 4; j++) tt[j] = *(const float2*)(etab + (size_t)r_[j] * D_C + lane * 2);
#pragma unroll
        for (int j = 0; j < 4; j++) {
            if (e + j < eend) {
                if (d_[j] != cur) {
                    ushort2 xr = *(const ushort2*)(x + (size_t)cur * D_C + lane * 2);
                    ushort2 o;
                    o.x = f2bits(bits2f(xr.x) + a0);
                    o.y = f2bits(bits2f(xr.y) + a1);
                    *(ushort2*)(xa + (size_t)cur * D_C + lane * 2) = o;
                    a0 = 0.0f; a1 = 0.0f; cur = d_[j];
                }
                a0 += fmaxf(bits2f(uu[j].x) + tt[j].x, 0.0f);
                a1 += fmaxf(bits2f(uu[j].y) + tt[j].y, 0.0f);
            }
        }
    }
    if (cur >= 0) {                    // final flush (always a plain store)
        ushort2 xr = *(const ushort2*)(x + (size_t)cur * D_C + lane * 2);
        ushort2 o;
        o.x = f2bits(bits2f(xr.x) + a0);
        o.y = f2bits(bits2f(xr.y) + a1);
        *(ushort2*)(xa + (size_t)cur * D_C + lane * 2) = o;
    }
    // zero-degree nodes in [nlo, nhi): XA = x
    int prev = estart;
    for (int nn = nlo; nn < nhi; nn++) {
        int se = offs[nn];
        if (se == prev) {
            *(ushort2*)(xa + (size_t)nn * D_C + lane * 2) =
                *(const ushort2*)(x + (size_t)nn * D_C + lane * 2);
        }
        prev = se;
    }
}

// ---- edge head, 4-wide quads: 13 units/edge (12 quads + 1 pair) ----
__global__ void edge_out_kernel(const int* __restrict__ flag,
                                const int* __restrict__ ei,
                                const unsigned short* __restrict__ PQ,
                                const void* __restrict__ eb,
                                void* __restrict__ out) {
    int isbf = *flag;
    long g = (long)blockIdx.x * blockDim.x + threadIdx.x;
    if (g >= (long)N_EDGES_C * 13) return;
    int e = (int)(g / 13);
    int jq = (int)(g - (long)e * 13);
    int src = ei[e];
    int dst = ei[N_EDGES_C + e];
    if (jq < 12) {
        int j = jq * 4;
        ushort4v us = *(const ushort4v*)(PQ + (size_t)src * 100 + j);
        ushort2v ud0 = *(const ushort2v*)(PQ + (size_t)dst * 100 + 50 + j);
        ushort2v ud1 = *(const ushort2v*)(PQ + (size_t)dst * 100 + 50 + j + 2);
        float v0 = bits2f(us.x) + bits2f(ud0.x) + ldf(eb, j, isbf);
        float v1 = bits2f(us.y) + bits2f(ud0.y) + ldf(eb, j + 1, isbf);
        float v2 = bits2f(us.z) + bits2f(ud1.x) + ldf(eb, j + 2, isbf);
        float v3 = bits2f(us.w) + bits2f(ud1.y) + ldf(eb, j + 3, isbf);
        if (isbf) {
            ushort2v o0; o0.x = f2bits(v0); o0.y = f2bits(v1);
            ushort2v o1; o1.x = f2bits(v2); o1.y = f2bits(v3);
            unsigned short* ob = (unsigned short*)out + EO_EDGE + (size_t)e * 50 + j;
            __builtin_nontemporal_store(o0, (ushort2v*)ob);
            __builtin_nontemporal_store(o1, (ushort2v*)(ob + 2));
        } else {
            float2v o0; o0.x = v0; o0.y = v1;
            float2v o1; o1.x = v2; o1.y = v3;
            float* ob = (float*)out + EO_EDGE + (size_t)e * 50 + j;
            __builtin_nontemporal_store(o0, (float2v*)ob);
            __builtin_nontemporal_store(o1, (float2v*)(ob + 2));
        }
    } else {
        int j = 48;
        ushort2v us = *(const ushort2v*)(PQ + (size_t)src * 100 + j);
        ushort2v ud = *(const ushort2v*)(PQ + (size_t)dst * 100 + 50 + j);
        float v0 = bits2f(us.x) + bits2f(ud.x) + ldf(eb, j, isbf);
        float v1 = bits2f(us.y) + bits2f(ud.y) + ldf(eb, j + 1, isbf);
        if (isbf) {
            ushort2v o; o.x = f2bits(v0); o.y = f2bits(v1);
            __builtin_nontemporal_store(o, (ushort2v*)((unsigned short*)out + EO_EDGE + (size_t)e * 50 + j));
        } else {
            float2v o; o.x = v0; o.y = v1;
            __builtin_nontemporal_store(o, (float2v*)((float*)out + EO_EDGE + (size_t)e * 50 + j));
        }
    }
}

__global__ void motif_kernel(const int* __restrict__ flag,
                             const int* __restrict__ cidx,
                             const bf16* __restrict__ x,
                             const void* __restrict__ W,
                             const void* __restrict__ bias,
                             void* __restrict__ out) {
    int isbf = *flag;
    int row = blockIdx.x;
    int t = threadIdx.x;
    __shared__ float sv[D_C];
    int id = cidx[row];
    sv[t] = b2f(x[(size_t)id * D_C + t]);
    __syncthreads();
    if (t < N_MOTIF_C) {
        float acc = ldf(bias, t, isbf);
        for (int k = 0; k < D_C; k++) acc = fmaf(sv[k], ldf(W, k * N_MOTIF_C + t, isbf), acc);
        stout_nt(out, EO_MOTIF + (size_t)row * N_MOTIF_C + t, isbf, acc);
    }
}

__global__ void nodec_kernel(const int* __restrict__ flag,
                             const int* __restrict__ nidx,
                             const bf16* __restrict__ x,
                             const void* __restrict__ W,
                             const void* __restrict__ bias,
                             void* __restrict__ out) {
    int isbf = *flag;
    int g = blockIdx.x * blockDim.x + threadIdx.x;
    if (g >= N_NONMOL_C * 15) return;
    int row = g / 15;
    int j = g - row * 15;
    int id = nidx[row];
    float acc = ldf(bias, j, isbf);
    for (int k = 0; k < D_C; k++) acc = fmaf(b2f(x[(size_t)id * D_C + k]), ldf(W, k * 15 + j, isbf), acc);
    stout_nt(out, EO_NODEC + g, isbf, acc);
}

__global__ void binary_kernel(const int* __restrict__ flag,
                              const bf16* __restrict__ x,
                              const void* __restrict__ W,
                              const void* __restrict__ bias,
                              void* __restrict__ out) {
    int isbf = *flag;
    int g = blockIdx.x * blockDim.x + threadIdx.x;
    int row = g >> 6;
    int lane = threadIdx.x & 63;
    if (row >= N_NODES_C) return;
    float a = b2f(x[(size_t)row * D_C + lane]) * ldf(W, lane, isbf) +
              b2f(x[(size_t)row * D_C + 64 + lane]) * ldf(W, 64 + lane, isbf);
#pragma unroll
    for (int off = 32; off > 0; off >>= 1) a += __shfl_down(a, off, 64);
    if (lane == 0) stout_nt(out, EO_BIN + row, isbf, a + ldf(bias, 0, isbf));
}

extern "C" void kernel_launch(void* const* d_in, const int* in_sizes, int n_in,
                              void* d_out, int out_size, void* d_ws, size_t ws_size,
                              hipStream_t stream) {
    const int* node_ids = (const int*)d_in[0];
    const int* rel_ids  = (const int*)d_in[1];
    const int* center   = (const int*)d_in[2];
    const int* nonmol   = (const int*)d_in[3];
    const int* ei       = (const int*)d_in[4];
    const void* node_emb = d_in[5];
    const void* rel_emb  = d_in[6];
    const void* lin_W = d_in[7];
    const void* lin_b = d_in[8];
    const void* W1 = d_in[9];
    const void* b1 = d_in[10];
    const void* W2 = d_in[11];
    const void* b2 = d_in[12];
    const void* edge_W = d_in[13];
    const void* edge_b = d_in[14];
    const void* motif_W = d_in[15];
    const void* motif_b = d_in[16];
    const void* nodec_W = d_in[17];
    const void* nodec_b = d_in[18];
    const void* bin_W = d_in[19];
    const void* bin_b = d_in[20];

    // ws: X0 [0,25.6MB), X1 [25.6,51.2MB), FLAG (4B)
    char* wsb = (char*)d_ws;
    unsigned short* X0 = (unsigned short*)wsb;
    unsigned short* X1 = (unsigned short*)(wsb + (size_t)N_NODES_C * D_C * 2);
    int* FLAG = (int*)(wsb + (size_t)2 * N_NODES_C * D_C * 2);
    unsigned short* PQ = X1;

    // scratch carved from dead d_out space
    char* ob = (char*)d_out;
    unsigned short* XA = (unsigned short*)(ob + XA_OFF);
    float* ET  = (float*)(ob + ET_OFF);
    unsigned short* WT0 = (unsigned short*)(ob + WT0_OFF);
    unsigned short* WT1 = (unsigned short*)(ob + WT1_OFF);
    unsigned short* WT2 = (unsigned short*)(ob + WT2_OFF);
    unsigned short* BPQ = (unsigned short*)(ob + BPQ_OFF);
    float* LB  = (float*)(ob + LB_OFF);
    float* B1p = (float*)(ob + B1_OFF);
    float* B2p = (float*)(ob + B2_OFF);
    int* OFFS = (int*)(ob + OFFS_OFF);
    int* BSUM = (int*)(ob + BSUM_OFF);
    int* SSRC = (int*)(ob + SSRC_OFF);
    int* SREL = (int*)(ob + SREL_OFF);
    int* SDST = (int*)(ob + SDST_OFF);
    int* NLO  = (int*)(ob + NLO_OFF);

    const int gemm_blocks = (N_NODES_C + 127) / 128;   // 782
    const int nscan = (N_NODES_C + 255) / 256;         // 391
    const int eblocks = (N_EDGES_C + 255) / 256;
    const int g2_blocks = (NW_C + 3) / 4;              // 4 waves/block

    probe_kernel<<<1, 256, 0, stream>>>(node_emb, FLAG);
    prepack_kernel<<<250, 256, 0, stream>>>(FLAG, lin_W, W1, W2, edge_W, lin_b, b1, b2,
                                            WT0, WT1, WT2, BPQ, LB, B1p, B2p);
    et_kernel<<<N_REL_C, D_C, 0, stream>>>(FLAG, rel_emb, lin_W, lin_b, ET);

    // ---- counting sort of edges by dst (reused by both convs) ----
    hipMemsetAsync(OFFS, 0, N_NODES_C * sizeof(int), stream);
    hist_kernel<<<eblocks, 256, 0, stream>>>(ei, OFFS);
    scan1_kernel<<<nscan, 256, 0, stream>>>(OFFS, BSUM);
    scan2_kernel<<<1, 512, 0, stream>>>(BSUM, nscan);
    scan3_kernel<<<nscan, 256, 0, stream>>>(OFFS, BSUM);
    sort_scatter_kernel<<<eblocks, 256, 0, stream>>>(ei, rel_ids, OFFS, SSRC, SREL, SDST);
    wave_part_kernel<<<(NW_C + 1 + 255) / 256, 256, 0, stream>>>(OFFS, NLO);

    // X0 = relu(l2norm(node_emb[node_ids]) @ lin_W + lin_b)  (normalize fused in)
    gemm0_norm_kernel<<<gemm_blocks, 256, 0, stream>>>(FLAG, node_ids, node_emb, WT0, LB, X0, N_NODES_C);

    // GINE conv 1: XA = X0 + agg(X0);  X1 = relu(XA @ W1 + b1)
    gather_fuse_kernel<<<g2_blocks, 256, 0, stream>>>(X0, OFFS, SSRC, SREL, SDST, NLO, ET, XA);
    gemm_kernel<128, true, false, true><<<gemm_blocks, 256, 0, stream>>>(XA, nullptr, WT1, B1p, X1, N_NODES_C);

    // GINE conv 2: XA = X1 + agg(X1);  X2(=X0 slot) = XA @ W2 + b2
    gather_fuse_kernel<<<g2_blocks, 256, 0, stream>>>(X1, OFFS, SSRC, SREL, SDST, NLO, ET, XA);
    gemm_kernel<128, false, false, true><<<gemm_blocks, 256, 0, stream>>>(XA, nullptr, WT2, B2p, X0, N_NODES_C);

    // PQ = X2 @ [edge_W halves]  -> [N,100]
    gemm_kernel<100, false, false, false><<<gemm_blocks, 256, 0, stream>>>(X0, nullptr, BPQ, nullptr, PQ, N_NODES_C);

    long ethreads = (long)N_EDGES_C * 13;   // 4-wide quads: 13 units per edge
    edge_out_kernel<<<(int)((ethreads + 255) / 256), 256, 0, stream>>>(FLAG, ei, PQ, edge_b, d_out);

    motif_kernel<<<N_CENTER_C, D_C, 0, stream>>>(FLAG, center, (const bf16*)X0, motif_W, motif_b, d_out);
    nodec_kernel<<<(N_NONMOL_C * 15 + 255) / 256, 256, 0, stream>>>(FLAG, nonmol, (const bf16*)X0, nodec_W, nodec_b, d_out);
    binary_kernel<<<(N_NODES_C * 64 + 255) / 256, 256, 0, stream>>>(FLAG, (const bf16*)X0, bin_W, bin_b, d_out);
}